// Round 7
// baseline (136.888 us; speedup 1.0000x reference)
//
#include <hip/hip_runtime.h>

// VQ: z [32,256,32,32] f32, codebook [1024,256] f32
// out: z_q [32,256,32,32] f32 (8388608) then loss scalar f32 (1)
#define NELEM 8388608

typedef __attribute__((ext_vector_type(4))) float f32x4;
typedef unsigned long long ull;

// ---------------------------------------------------------------------------
// prep: codebook -> fp8 e4m3 (scaled x256, exact pow2) in B-fragment-linear
// order for mfma_f32_16x16x32_fp8_fp8, plus exact fp32 norms cn[k].
// frag g = nt*8+ks (512 B): lane L holds cb[nt*16+(L&15)][ks*32+(L>>4)*8+0..7]
// Also zeroes the loss scalar.
__global__ __launch_bounds__(256) void prep_kernel(const float* __restrict__ cb,
                                                   uint2* __restrict__ cbf8,
                                                   float* __restrict__ cn,
                                                   float* __restrict__ loss) {
    if (blockIdx.x == 0 && threadIdx.x == 0) *loss = 0.f;

    const int t = threadIdx.x;
    const int gt = blockIdx.x * 256 + t;          // 0..32767
    const int L = gt & 63, g = gt >> 6;           // frag 0..511
    const int nt = g >> 3, ks = g & 7;
    const int code = nt * 16 + (L & 15);
    const int k0 = ks * 32 + (L >> 4) * 8;
    const float* s = cb + code * 256 + k0;
    float v[8];
    #pragma unroll
    for (int j = 0; j < 8; ++j) v[j] = s[j] * 256.0f;
    int lo = 0, hi = 0;
    lo = __builtin_amdgcn_cvt_pk_fp8_f32(v[0], v[1], lo, false);
    lo = __builtin_amdgcn_cvt_pk_fp8_f32(v[2], v[3], lo, true);
    hi = __builtin_amdgcn_cvt_pk_fp8_f32(v[4], v[5], hi, false);
    hi = __builtin_amdgcn_cvt_pk_fp8_f32(v[6], v[7], hi, true);
    uint2 o; o.x = (unsigned)lo; o.y = (unsigned)hi;
    cbf8[g * 64 + L] = o;

    const int w = t >> 6, lane = t & 63;
    #pragma unroll
    for (int cc = 0; cc < 2; ++cc) {
        int cd = blockIdx.x * 8 + w * 2 + cc;
        float4 qv = *(const float4*)(cb + cd * 256 + lane * 4);
        float s2 = qv.x*qv.x + qv.y*qv.y + qv.z*qv.z + qv.w*qv.w;
        #pragma unroll
        for (int off = 32; off; off >>= 1) s2 += __shfl_down(s2, off, 64);
        if (lane == 0) cn[cd] = s2;
    }
}

// ---------------------------------------------------------------------------
// k1 zprep: z -> fp8 A-frags in ws (MFMA-A-linear layout) + exact z^2 loss.
// Block = 32 pos x 256 ch. Stage z COALESCED (each 128-B channel row read as
// 8 lanes x float4) into LDS [256][34] (<=2-way banks), then build frags
// from LDS. Replaces the 16x stride-4KB scalar gather every prior round
// shared. af_ws[mt][ks][64] ull: lane L holds z[pos=mt*16+(L&15)]
// [k=ks*32+(L>>4)*8+0..7] as fp8 x16. Writes 512 B coalesced rows.
__global__ __launch_bounds__(256) void zprep_kernel(const float* __restrict__ z,
                                                    ull* __restrict__ af_ws,
                                                    float* __restrict__ loss) {
    __shared__ float zS[256][34];     // 34.8 KB; stride 34: banks <=2-way
    __shared__ float wsum[4];
    const int t = threadIdx.x, w = t >> 6, L = t & 63;
    const int blk = blockIdx.x;                 // 0..1023
    const int b = blk >> 5, hw0 = (blk & 31) << 5;
    const float* zb = z + ((size_t)b << 18) + hw0;

    // coalesced stage: per inst, 8 channel rows x 128 B (full lines)
    #pragma unroll
    for (int i = 0; i < 8; ++i) {
        int c = (w << 6) + (i << 3) + (L >> 3);
        float4 v = *(const float4*)(zb + ((size_t)c << 10) + ((L & 7) << 2));
        float* qp = &zS[c][(L & 7) << 2];
        qp[0] = v.x; qp[1] = v.y; qp[2] = v.z; qp[3] = v.w;
    }
    __syncthreads();

    // frag build: wave w -> mtile mi = w&1, ks-half ksh = w>>1 (exact cover)
    const int col = L & 15, q = L >> 4;
    const int mi = w & 1, ksh = w >> 1;
    const int pl = mi * 16 + col;               // pos within block
    const int mt = (blk << 1) + mi;             // global m-tile 0..2047
    float z2 = 0.f;
    #pragma unroll
    for (int kk = 0; kk < 4; ++kk) {
        int ks = ksh * 4 + kk;
        int k0 = ks * 32 + q * 8;
        float v[8];
        #pragma unroll
        for (int j = 0; j < 8; ++j) v[j] = zS[k0 + j][pl];
        #pragma unroll
        for (int j = 0; j < 8; ++j) z2 += v[j] * v[j];
        int lo = 0, hi = 0;
        lo = __builtin_amdgcn_cvt_pk_fp8_f32(v[0]*16.f, v[1]*16.f, lo, false);
        lo = __builtin_amdgcn_cvt_pk_fp8_f32(v[2]*16.f, v[3]*16.f, lo, true);
        hi = __builtin_amdgcn_cvt_pk_fp8_f32(v[4]*16.f, v[5]*16.f, hi, false);
        hi = __builtin_amdgcn_cvt_pk_fp8_f32(v[6]*16.f, v[7]*16.f, hi, true);
        af_ws[(((mt << 3) + ks) << 6) + L] = ((ull)(unsigned)hi << 32) | (unsigned)lo;
    }

    #pragma unroll
    for (int off = 32; off; off >>= 1) z2 += __shfl_down(z2, off, 64);
    if (L == 0) wsum[w] = z2;
    __syncthreads();
    if (t == 0)
        atomicAdd(loss, (wsum[0] + wsum[1] + wsum[2] + wsum[3]) * (1.25f / (float)NELEM));
}

// ---------------------------------------------------------------------------
// k2 argmin: r6's proven loop body, standalone. Block = 32 pos x 1024 codes,
// 4 waves; wave w holds BOTH m-frags (loaded coalesced from af_ws, no LDS
// exchange) and iterates code-quarter nt in [w*16, w*16+16). Loop is
// barrier-free; B frags straight from L2 (cbf8 256 KB resident). dist =
// cn - 2*dot (SC = -2/(16*256)); nt packed in 6 low mantissa bits.
// Emits per-pos code -> codes_ws and dmin-sum -> loss atomic.
__global__ __launch_bounds__(256) void argmin_kernel(
        const ull* __restrict__ bg, const ull* __restrict__ af_ws,
        const float* __restrict__ cn, int* __restrict__ codes,
        float* __restrict__ loss) {
    __shared__ float cnS[1024];
    __shared__ float Dw[4][32];
    __shared__ int   Cw[4][32];
    const int t = threadIdx.x, w = t >> 6, L = t & 63;
    const int col = L & 15, q = L >> 4;
    const int blk = blockIdx.x;                 // 0..1023

    *(float4*)&cnS[t * 4] = *(const float4*)(cn + t * 4);

    ull am[2][8];
    #pragma unroll
    for (int m2 = 0; m2 < 2; ++m2)
        #pragma unroll
        for (int ks = 0; ks < 8; ++ks)
            am[m2][ks] = af_ws[(((((blk << 1) + m2) << 3) + ks) << 6) + L];

    __syncthreads();

    float minv[2][4];
    #pragma unroll
    for (int m2 = 0; m2 < 2; ++m2)
        #pragma unroll
        for (int r = 0; r < 4; ++r) minv[m2][r] = 3.4e38f;

    const float SC = -4.8828125e-4f;   // -2 / (16*256)
    #pragma unroll 1
    for (int it = 0; it < 16; ++it) {
        const int nt = (w << 4) + it;
        ull breg[8];
        #pragma unroll
        for (int ks = 0; ks < 8; ++ks)
            breg[ks] = bg[(((nt << 3) + ks) << 6) + L];
        const float cnv = cnS[(nt << 4) + col];

        f32x4 a0 = {0,0,0,0}, a0b = {0,0,0,0}, a1 = {0,0,0,0}, a1b = {0,0,0,0};
        #pragma unroll
        for (int kk = 0; kk < 4; ++kk) {
            a0  = __builtin_amdgcn_mfma_f32_16x16x32_fp8_fp8((long long)am[0][2*kk],   (long long)breg[2*kk],   a0,  0, 0, 0);
            a0b = __builtin_amdgcn_mfma_f32_16x16x32_fp8_fp8((long long)am[0][2*kk+1], (long long)breg[2*kk+1], a0b, 0, 0, 0);
            a1  = __builtin_amdgcn_mfma_f32_16x16x32_fp8_fp8((long long)am[1][2*kk],   (long long)breg[2*kk],   a1,  0, 0, 0);
            a1b = __builtin_amdgcn_mfma_f32_16x16x32_fp8_fp8((long long)am[1][2*kk+1], (long long)breg[2*kk+1], a1b, 0, 0, 0);
        }
        a0 = a0 + a0b;
        a1 = a1 + a1b;

        const unsigned pn = (unsigned)nt;                  // 6 bits
        #pragma unroll
        for (int m2 = 0; m2 < 2; ++m2) {
            const f32x4& aa = m2 ? a1 : a0;
            #pragma unroll
            for (int r = 0; r < 4; ++r) {
                float d = fmaf(SC, aa[r], cnv);
                d = __uint_as_float((__float_as_uint(d) & ~63u) | pn);
                minv[m2][r] = fminf(minv[m2][r], d);
            }
        }
    }

    // within-wave min over the 16 code-cols; winners -> LDS
    #pragma unroll
    for (int m2 = 0; m2 < 2; ++m2) {
        #pragma unroll
        for (int r = 0; r < 4; ++r) {
            float v = minv[m2][r];
            int cd = ((__float_as_int(v) & 63) << 4) | col;
            #pragma unroll
            for (int d = 1; d < 16; d <<= 1) {
                float ov = __shfl_xor(v, d, 64);
                int   oc = __shfl_xor(cd, d, 64);
                if (ov < v || (ov == v && oc < cd)) { v = ov; cd = oc; }
            }
            if (col == 0) {
                int p = m2 * 16 + q * 4 + r;   // position 0..31
                Dw[w][p] = v;
                Cw[w][p] = cd;
            }
        }
    }
    __syncthreads();

    // cross-wave min (each wave held a disjoint quarter of the codes)
    if (w == 0) {
        float dpart = 0.f;
        if (L < 32) {
            float v = Dw[0][L]; int cd = Cw[0][L];
            #pragma unroll
            for (int ww = 1; ww < 4; ++ww) {
                float ov = Dw[ww][L]; int oc = Cw[ww][L];
                if (ov < v || (ov == v && oc < cd)) { v = ov; cd = oc; }
            }
            codes[(blk << 5) + L] = cd;
            dpart = __uint_as_float(__float_as_uint(v) & ~63u);
        }
        #pragma unroll
        for (int off = 16; off; off >>= 1) dpart += __shfl_down(dpart, off, 64);
        if (L == 0) atomicAdd(loss, dpart * (1.25f / (float)NELEM));
    }
}

// ---------------------------------------------------------------------------
// k3 gather: codebook-row gather + transpose + coalesced store (r1's proven
// epilogue, standalone). Block = 32 pos; 128-B contiguous output segments.
__global__ __launch_bounds__(256) void gather_kernel(
        const float* __restrict__ cb, const int* __restrict__ codes,
        float* __restrict__ out) {
    __shared__ float Q[32][257];               // 32.9 KB
    __shared__ int codeS[32];
    const int t = threadIdx.x, w = t >> 6, L = t & 63;
    const int blk = blockIdx.x;                 // 0..1023
    const int b = blk >> 5, hw0 = (blk & 31) << 5;

    if (t < 32) codeS[t] = codes[(blk << 5) + t];
    __syncthreads();

    #pragma unroll
    for (int rr = 0; rr < 8; ++rr) {
        int row = (w << 3) + rr;               // 0..31
        int code = codeS[row];
        float4 v = *(const float4*)(cb + ((size_t)code << 8) + (L << 2));
        float* qp = &Q[row][L << 2];
        qp[0] = v.x; qp[1] = v.y; qp[2] = v.z; qp[3] = v.w;
    }
    __syncthreads();

    const size_t obase = ((size_t)b << 18) + hw0;
    const int pg = L & 7, cidx = L >> 3;
    #pragma unroll
    for (int i = 0; i < 8; ++i) {
        int c = (w << 6) + (i << 3) + cidx;
        int p0 = pg << 2;
        float4 qv;
        qv.x = Q[p0 + 0][c]; qv.y = Q[p0 + 1][c];
        qv.z = Q[p0 + 2][c]; qv.w = Q[p0 + 3][c];
        *(float4*)(out + obase + ((size_t)c << 10) + p0) = qv;
    }
}

// ---------------------------------------------------------------------------
extern "C" void kernel_launch(void* const* d_in, const int* in_sizes, int n_in,
                              void* d_out, int out_size, void* d_ws, size_t ws_size,
                              hipStream_t stream) {
    const float* z  = (const float*)d_in[0];
    const float* cb = (const float*)d_in[1];
    float* out  = (float*)d_out;
    float* cn   = (float*)d_ws;                              // 4 KB
    uint2* cbf8 = (uint2*)((char*)d_ws + 4096);              // 256 KB
    ull*   afw  = (ull*)((char*)d_ws + 524288);              // 8 MB frags
    int*   cds  = (int*)((char*)d_ws + 524288 + 8388608);    // 128 KB codes
    float* loss = out + NELEM;

    prep_kernel<<<128, 256, 0, stream>>>(cb, cbf8, cn, loss);
    zprep_kernel<<<1024, 256, 0, stream>>>(z, afw, loss);
    argmin_kernel<<<1024, 256, 0, stream>>>((const ull*)cbf8, afw, cn, cds, loss);
    gather_kernel<<<1024, 256, 0, stream>>>(cb, cds, out);
}

// Round 8
// 108.460 us; speedup vs baseline: 1.2621x; 1.2621x over previous
//
#include <hip/hip_runtime.h>

// VQ: z [32,256,32,32] f32, codebook [1024,256] f32
// out: z_q [32,256,32,32] f32 (8388608) then loss scalar f32 (1)
#define NELEM 8388608

typedef __attribute__((ext_vector_type(4))) float f32x4;
typedef unsigned long long ull;

// ---------------------------------------------------------------------------
// prep: codebook -> fp8 e4m3 (scaled x256, exact pow2) in B-fragment-linear
// order for mfma_f32_16x16x32_fp8_fp8, plus exact fp32 norms cn[k].
// frag g = nt*8+ks (512 B): lane L holds cb[nt*16+(L&15)][ks*32+(L>>4)*8+0..7]
// Also zeroes the loss scalar (replaces the separate hipMemsetAsync dispatch
// -- the one delta vs the measured-best r0 baseline; proven safe r1-r7).
__global__ __launch_bounds__(256) void prep_kernel(const float* __restrict__ cb,
                                                   uint2* __restrict__ cbf8,
                                                   float* __restrict__ cn,
                                                   float* __restrict__ loss) {
    if (blockIdx.x == 0 && threadIdx.x == 0) *loss = 0.f;

    const int t = threadIdx.x;
    const int gt = blockIdx.x * 256 + t;          // 0..32767
    const int L = gt & 63, g = gt >> 6;           // frag 0..511
    const int nt = g >> 3, ks = g & 7;
    const int code = nt * 16 + (L & 15);
    const int k0 = ks * 32 + (L >> 4) * 8;
    const float* s = cb + code * 256 + k0;
    float v[8];
    #pragma unroll
    for (int j = 0; j < 8; ++j) v[j] = s[j] * 256.0f;
    int lo = 0, hi = 0;
    lo = __builtin_amdgcn_cvt_pk_fp8_f32(v[0], v[1], lo, false);
    lo = __builtin_amdgcn_cvt_pk_fp8_f32(v[2], v[3], lo, true);
    hi = __builtin_amdgcn_cvt_pk_fp8_f32(v[4], v[5], hi, false);
    hi = __builtin_amdgcn_cvt_pk_fp8_f32(v[6], v[7], hi, true);
    uint2 o; o.x = (unsigned)lo; o.y = (unsigned)hi;
    cbf8[g * 64 + L] = o;

    const int w = t >> 6, lane = t & 63;
    #pragma unroll
    for (int cc = 0; cc < 2; ++cc) {
        int cd = blockIdx.x * 8 + w * 2 + cc;
        float4 qv = *(const float4*)(cb + cd * 256 + lane * 4);
        float s2 = qv.x*qv.x + qv.y*qv.y + qv.z*qv.z + qv.w*qv.w;
        #pragma unroll
        for (int off = 32; off; off >>= 1) s2 += __shfl_down(s2, off, 64);
        if (lane == 0) cn[cd] = s2;
    }
}

// ---------------------------------------------------------------------------
// Fused argmin + gather + transpose-store + loss. (r0 measured-best kernel,
// restored verbatim: 6 restructures -- A-exchange, forced occupancy, DMA
// staging, 2-ahead prefetch, L2-direct, 8-wave blocks -- all measured equal
// or worse; this structure's 64 MFMA/iter covers B-prefetch latency.)
// Grid 512 blocks x 256 thr, 2 blocks/CU (LDS 36 KB). Block = 64 pos x 1024
// codes, K=256 resident in regs (fp8 x16). B chunks (4 nt = 16 KB) double-
// buffered in LDS. dist = cn - 2*dot; nt packed into 6 low mantissa bits.
// loss = 1.25/NELEM * sum(z^2_exact + dmin).
__global__ __launch_bounds__(256, 2) void vq_kernel(
        const float* __restrict__ z, const uint4* __restrict__ cbf8,
        const float* __restrict__ cb, const float* __restrict__ cn,
        float* __restrict__ out, float* __restrict__ loss) {
    __shared__ union {
        struct { float cn[1024]; uint4 B[2][1024]; } p1;   // 4 + 2x16 KB
        float Q[32][257];                                  // 32.9 KB
    } S;
    __shared__ int codeS[64];
    __shared__ float wsum[4];

    const int t = threadIdx.x, w = t >> 6, L = t & 63;
    const int col = L & 15, q = L >> 4;
    const int blk = blockIdx.x;
    const int b = blk >> 4, hw0 = (blk & 15) << 6;

    // stage cn
    *(float4*)&S.p1.cn[t * 4] = *(const float4*)(cn + t * 4);

    // B chunk 0 global loads (issue early, store after A phase)
    uint4 st0[4];
    #pragma unroll
    for (int i = 0; i < 4; ++i) st0[i] = cbf8[(i << 8) + t];

    // A-frags: wave w owns pos w*16..w*16+15 (1 m-frag). z scaled x16 -> fp8.
    // Exact fp32 z^2 accumulated from the same loads.
    ull af[8];
    float z2 = 0.f;
    const float* zb = z + ((size_t)b << 18) + hw0;
    {
        const float* zp = zb + (w * 16 + col) + ((q * 8) << 10);
        #pragma unroll
        for (int ks = 0; ks < 8; ++ks) {
            const float* sp = zp + ((ks * 32) << 10);
            float v[8];
            #pragma unroll
            for (int j = 0; j < 8; ++j) v[j] = sp[j << 10];
            #pragma unroll
            for (int j = 0; j < 8; ++j) z2 += v[j] * v[j];
            int lo = 0, hi = 0;
            lo = __builtin_amdgcn_cvt_pk_fp8_f32(v[0]*16.f, v[1]*16.f, lo, false);
            lo = __builtin_amdgcn_cvt_pk_fp8_f32(v[2]*16.f, v[3]*16.f, lo, true);
            hi = __builtin_amdgcn_cvt_pk_fp8_f32(v[4]*16.f, v[5]*16.f, hi, false);
            hi = __builtin_amdgcn_cvt_pk_fp8_f32(v[6]*16.f, v[7]*16.f, hi, true);
            af[ks] = ((ull)(unsigned)hi << 32) | (unsigned)lo;
        }
    }

    #pragma unroll
    for (int i = 0; i < 4; ++i) S.p1.B[0][(i << 8) + t] = st0[i];

    float minv[4];
    #pragma unroll
    for (int r = 0; r < 4; ++r) minv[r] = 3.4e38f;

    __syncthreads();

    const float SC = -4.8828125e-4f;   // -2 / (16*256)
    for (int it = 0; it < 16; ++it) {
        const int cur = it & 1;
        uint4 st2[4];
        if (it < 15) {
            #pragma unroll
            for (int i = 0; i < 4; ++i) st2[i] = cbf8[((it + 1) << 10) + (i << 8) + t];
        }
        const ull* bb = (const ull*)&S.p1.B[cur][0];
        ull breg[4][8];
        #pragma unroll
        for (int n2 = 0; n2 < 4; ++n2)
            #pragma unroll
            for (int ks = 0; ks < 8; ++ks)
                breg[n2][ks] = bb[(n2 * 8 + ks) * 64 + L];

        f32x4 a0 = {0,0,0,0}, a1 = {0,0,0,0}, a2 = {0,0,0,0}, a3 = {0,0,0,0};
        #pragma unroll
        for (int ks = 0; ks < 8; ++ks) {            // 4 independent chains
            a0 = __builtin_amdgcn_mfma_f32_16x16x32_fp8_fp8((long long)af[ks], (long long)breg[0][ks], a0, 0, 0, 0);
            a1 = __builtin_amdgcn_mfma_f32_16x16x32_fp8_fp8((long long)af[ks], (long long)breg[1][ks], a1, 0, 0, 0);
            a2 = __builtin_amdgcn_mfma_f32_16x16x32_fp8_fp8((long long)af[ks], (long long)breg[2][ks], a2, 0, 0, 0);
            a3 = __builtin_amdgcn_mfma_f32_16x16x32_fp8_fp8((long long)af[ks], (long long)breg[3][ks], a3, 0, 0, 0);
        }
        const int ntb = it * 4;
        #pragma unroll
        for (int n2 = 0; n2 < 4; ++n2) {
            const f32x4& aa = (n2 == 0) ? a0 : (n2 == 1) ? a1 : (n2 == 2) ? a2 : a3;
            const float cnv = S.p1.cn[(ntb + n2) * 16 + col];
            const unsigned pn = (unsigned)(ntb + n2);
            #pragma unroll
            for (int r = 0; r < 4; ++r) {
                float d = fmaf(SC, aa[r], cnv);
                d = __uint_as_float((__float_as_uint(d) & ~63u) | pn);
                minv[r] = fminf(minv[r], d);
            }
        }
        if (it < 15) {
            #pragma unroll
            for (int i = 0; i < 4; ++i) S.p1.B[cur ^ 1][(i << 8) + t] = st2[i];
        }
        __syncthreads();
    }

    // cross-lane min over the 16 code-cols; emit per-pos code + dmin
    float dpart = 0.f;
    #pragma unroll
    for (int r = 0; r < 4; ++r) {
        float v = minv[r];
        int cd = ((__float_as_int(v) & 63) << 4) | col;
        #pragma unroll
        for (int d = 1; d < 16; d <<= 1) {
            float ov = __shfl_xor(v, d, 64);
            int   oc = __shfl_xor(cd, d, 64);
            if (ov < v || (ov == v && oc < cd)) { v = ov; cd = oc; }
        }
        if (col == 0) {
            codeS[w * 16 + q * 4 + r] = cd;
            dpart += __uint_as_float(__float_as_uint(v) & ~63u);
        }
    }

    float tot = z2 + dpart;
    #pragma unroll
    for (int off = 32; off; off >>= 1) tot += __shfl_down(tot, off, 64);
    if (L == 0) wsum[w] = tot;
    __syncthreads();
    if (t == 0)
        atomicAdd(loss, (wsum[0] + wsum[1] + wsum[2] + wsum[3]) * (1.25f / (float)NELEM));

    // Phase C/D: gather fp32 codebook rows (coalesced), transpose via LDS,
    // write out. Two 32-pos chunks so Q fits the 36 KB union.
    const size_t obase = ((size_t)b << 18) + hw0;
    const int pg = L & 7, cidx = L >> 3;
    #pragma unroll
    for (int ch = 0; ch < 2; ++ch) {
        __syncthreads();
        #pragma unroll
        for (int rr = 0; rr < 8; ++rr) {
            int row = w * 8 + rr;
            int code = codeS[ch * 32 + row];
            float4 v = *(const float4*)(cb + ((size_t)code << 8) + (L << 2));
            float* qp = &S.Q[row][L << 2];
            qp[0] = v.x; qp[1] = v.y; qp[2] = v.z; qp[3] = v.w;
        }
        __syncthreads();
        #pragma unroll
        for (int i = 0; i < 8; ++i) {
            int c = w * 64 + i * 8 + cidx;
            int p0 = pg * 4;
            float4 qv;
            qv.x = S.Q[p0 + 0][c]; qv.y = S.Q[p0 + 1][c];
            qv.z = S.Q[p0 + 2][c]; qv.w = S.Q[p0 + 3][c];
            *(float4*)(out + obase + ((size_t)c << 10) + ch * 32 + p0) = qv;
        }
    }
}

// ---------------------------------------------------------------------------
extern "C" void kernel_launch(void* const* d_in, const int* in_sizes, int n_in,
                              void* d_out, int out_size, void* d_ws, size_t ws_size,
                              hipStream_t stream) {
    const float* z  = (const float*)d_in[0];
    const float* cb = (const float*)d_in[1];
    float* out  = (float*)d_out;
    float* cn   = (float*)d_ws;                              // 4 KB
    uint2* cbf8 = (uint2*)((char*)d_ws + 4096);              // 256 KB
    float* loss = out + NELEM;

    prep_kernel<<<128, 256, 0, stream>>>(cb, cbf8, cn, loss);
    vq_kernel<<<512, 256, 0, stream>>>(z, (const uint4*)cbf8, cb, cn, out, loss);
}

// Round 12
// 106.896 us; speedup vs baseline: 1.2806x; 1.0146x over previous
//
#include <hip/hip_runtime.h>

// VQ: z [32,256,32,32] f32, codebook [1024,256] f32
// out: z_q [32,256,32,32] f32 (8388608) then loss scalar f32 (1)
#define NELEM 8388608

typedef __attribute__((ext_vector_type(4))) float f32x4;
typedef unsigned long long ull;

// ---------------------------------------------------------------------------
// prep: codebook -> fp8 e4m3 (scaled x256, exact pow2) in B-fragment-linear
// order for mfma_f32_16x16x32_fp8_fp8, plus exact fp32 norms cn[k].
// frag g = nt*8+ks (512 B): lane L holds cb[nt*16+(L&15)][ks*32+(L>>4)*8+0..7]
// Also zeroes the loss scalar (replaces the separate hipMemsetAsync dispatch;
// safe here because the kernel boundary flushes L2 before vq's atomicAdds --
// r9/r10 showed single-kernel zeroing + cooperative sync breaks under the
// harness's graph replay).
__global__ __launch_bounds__(256) void prep_kernel(const float* __restrict__ cb,
                                                   uint2* __restrict__ cbf8,
                                                   float* __restrict__ cn,
                                                   float* __restrict__ loss) {
    if (blockIdx.x == 0 && threadIdx.x == 0) *loss = 0.f;

    const int t = threadIdx.x;
    const int gt = blockIdx.x * 256 + t;          // 0..32767
    const int L = gt & 63, g = gt >> 6;           // frag 0..511
    const int nt = g >> 3, ks = g & 7;
    const int code = nt * 16 + (L & 15);
    const int k0 = ks * 32 + (L >> 4) * 8;
    const float* s = cb + code * 256 + k0;
    float v[8];
    #pragma unroll
    for (int j = 0; j < 8; ++j) v[j] = s[j] * 256.0f;
    int lo = 0, hi = 0;
    lo = __builtin_amdgcn_cvt_pk_fp8_f32(v[0], v[1], lo, false);
    lo = __builtin_amdgcn_cvt_pk_fp8_f32(v[2], v[3], lo, true);
    hi = __builtin_amdgcn_cvt_pk_fp8_f32(v[4], v[5], hi, false);
    hi = __builtin_amdgcn_cvt_pk_fp8_f32(v[6], v[7], hi, true);
    uint2 o; o.x = (unsigned)lo; o.y = (unsigned)hi;
    cbf8[g * 64 + L] = o;

    const int w = t >> 6, lane = t & 63;
    #pragma unroll
    for (int cc = 0; cc < 2; ++cc) {
        int cd = blockIdx.x * 8 + w * 2 + cc;
        float4 qv = *(const float4*)(cb + cd * 256 + lane * 4);
        float s2 = qv.x*qv.x + qv.y*qv.y + qv.z*qv.z + qv.w*qv.w;
        #pragma unroll
        for (int off = 32; off; off >>= 1) s2 += __shfl_down(s2, off, 64);
        if (lane == 0) cn[cd] = s2;
    }
}

// ---------------------------------------------------------------------------
// Fused argmin + gather + transpose-store + loss. (Measured-best structure:
// 6 restructures -- A-exchange, forced occupancy, DMA staging, 2-ahead
// prefetch, L2-direct, 8-wave blocks, kernel split, cooperative fusion --
// all measured equal or worse; this structure's 64 MFMA/iter covers
// B-prefetch latency.)
// Grid 512 blocks x 256 thr, 2 blocks/CU (LDS 36 KB). Block = 64 pos x 1024
// codes, K=256 resident in regs (fp8 x16). B chunks (4 nt = 16 KB) double-
// buffered in LDS. dist = cn - 2*dot; nt packed into 6 low mantissa bits.
// loss = 1.25/NELEM * sum(z^2_exact + dmin).
__global__ __launch_bounds__(256, 2) void vq_kernel(
        const float* __restrict__ z, const uint4* __restrict__ cbf8,
        const float* __restrict__ cb, const float* __restrict__ cn,
        float* __restrict__ out, float* __restrict__ loss) {
    __shared__ union {
        struct { float cn[1024]; uint4 B[2][1024]; } p1;   // 4 + 2x16 KB
        float Q[32][257];                                  // 32.9 KB
    } S;
    __shared__ int codeS[64];
    __shared__ float wsum[4];

    const int t = threadIdx.x, w = t >> 6, L = t & 63;
    const int col = L & 15, q = L >> 4;
    const int blk = blockIdx.x;
    const int b = blk >> 4, hw0 = (blk & 15) << 6;

    // stage cn
    *(float4*)&S.p1.cn[t * 4] = *(const float4*)(cn + t * 4);

    // B chunk 0 global loads (issue early, store after A phase)
    uint4 st0[4];
    #pragma unroll
    for (int i = 0; i < 4; ++i) st0[i] = cbf8[(i << 8) + t];

    // A-frags: wave w owns pos w*16..w*16+15 (1 m-frag). z scaled x16 -> fp8.
    // Exact fp32 z^2 accumulated from the same loads.
    ull af[8];
    float z2 = 0.f;
    const float* zb = z + ((size_t)b << 18) + hw0;
    {
        const float* zp = zb + (w * 16 + col) + ((q * 8) << 10);
        #pragma unroll
        for (int ks = 0; ks < 8; ++ks) {
            const float* sp = zp + ((ks * 32) << 10);
            float v[8];
            #pragma unroll
            for (int j = 0; j < 8; ++j) v[j] = sp[j << 10];
            #pragma unroll
            for (int j = 0; j < 8; ++j) z2 += v[j] * v[j];
            int lo = 0, hi = 0;
            lo = __builtin_amdgcn_cvt_pk_fp8_f32(v[0]*16.f, v[1]*16.f, lo, false);
            lo = __builtin_amdgcn_cvt_pk_fp8_f32(v[2]*16.f, v[3]*16.f, lo, true);
            hi = __builtin_amdgcn_cvt_pk_fp8_f32(v[4]*16.f, v[5]*16.f, hi, false);
            hi = __builtin_amdgcn_cvt_pk_fp8_f32(v[6]*16.f, v[7]*16.f, hi, true);
            af[ks] = ((ull)(unsigned)hi << 32) | (unsigned)lo;
        }
    }

    #pragma unroll
    for (int i = 0; i < 4; ++i) S.p1.B[0][(i << 8) + t] = st0[i];

    float minv[4];
    #pragma unroll
    for (int r = 0; r < 4; ++r) minv[r] = 3.4e38f;

    __syncthreads();

    const float SC = -4.8828125e-4f;   // -2 / (16*256)
    for (int it = 0; it < 16; ++it) {
        const int cur = it & 1;
        uint4 st2[4];
        if (it < 15) {
            #pragma unroll
            for (int i = 0; i < 4; ++i) st2[i] = cbf8[((it + 1) << 10) + (i << 8) + t];
        }
        const ull* bb = (const ull*)&S.p1.B[cur][0];
        ull breg[4][8];
        #pragma unroll
        for (int n2 = 0; n2 < 4; ++n2)
            #pragma unroll
            for (int ks = 0; ks < 8; ++ks)
                breg[n2][ks] = bb[(n2 * 8 + ks) * 64 + L];

        f32x4 a0 = {0,0,0,0}, a1 = {0,0,0,0}, a2 = {0,0,0,0}, a3 = {0,0,0,0};
        #pragma unroll
        for (int ks = 0; ks < 8; ++ks) {            // 4 independent chains
            a0 = __builtin_amdgcn_mfma_f32_16x16x32_fp8_fp8((long long)af[ks], (long long)breg[0][ks], a0, 0, 0, 0);
            a1 = __builtin_amdgcn_mfma_f32_16x16x32_fp8_fp8((long long)af[ks], (long long)breg[1][ks], a1, 0, 0, 0);
            a2 = __builtin_amdgcn_mfma_f32_16x16x32_fp8_fp8((long long)af[ks], (long long)breg[2][ks], a2, 0, 0, 0);
            a3 = __builtin_amdgcn_mfma_f32_16x16x32_fp8_fp8((long long)af[ks], (long long)breg[3][ks], a3, 0, 0, 0);
        }
        const int ntb = it * 4;
        #pragma unroll
        for (int n2 = 0; n2 < 4; ++n2) {
            const f32x4& aa = (n2 == 0) ? a0 : (n2 == 1) ? a1 : (n2 == 2) ? a2 : a3;
            const float cnv = S.p1.cn[(ntb + n2) * 16 + col];
            const unsigned pn = (unsigned)(ntb + n2);
            #pragma unroll
            for (int r = 0; r < 4; ++r) {
                float d = fmaf(SC, aa[r], cnv);
                d = __uint_as_float((__float_as_uint(d) & ~63u) | pn);
                minv[r] = fminf(minv[r], d);
            }
        }
        if (it < 15) {
            #pragma unroll
            for (int i = 0; i < 4; ++i) S.p1.B[cur ^ 1][(i << 8) + t] = st2[i];
        }
        __syncthreads();
    }

    // cross-lane min over the 16 code-cols; emit per-pos code + dmin
    float dpart = 0.f;
    #pragma unroll
    for (int r = 0; r < 4; ++r) {
        float v = minv[r];
        int cd = ((__float_as_int(v) & 63) << 4) | col;
        #pragma unroll
        for (int d = 1; d < 16; d <<= 1) {
            float ov = __shfl_xor(v, d, 64);
            int   oc = __shfl_xor(cd, d, 64);
            if (ov < v || (ov == v && oc < cd)) { v = ov; cd = oc; }
        }
        if (col == 0) {
            codeS[w * 16 + q * 4 + r] = cd;
            dpart += __uint_as_float(__float_as_uint(v) & ~63u);
        }
    }

    float tot = z2 + dpart;
    #pragma unroll
    for (int off = 32; off; off >>= 1) tot += __shfl_down(tot, off, 64);
    if (L == 0) wsum[w] = tot;
    __syncthreads();
    if (t == 0)
        atomicAdd(loss, (wsum[0] + wsum[1] + wsum[2] + wsum[3]) * (1.25f / (float)NELEM));

    // Phase C/D: gather fp32 codebook rows (coalesced), transpose via LDS,
    // write out. Two 32-pos chunks so Q fits the 36 KB union.
    const size_t obase = ((size_t)b << 18) + hw0;
    const int pg = L & 7, cidx = L >> 3;
    #pragma unroll
    for (int ch = 0; ch < 2; ++ch) {
        __syncthreads();
        #pragma unroll
        for (int rr = 0; rr < 8; ++rr) {
            int row = w * 8 + rr;
            int code = codeS[ch * 32 + row];
            float4 v = *(const float4*)(cb + ((size_t)code << 8) + (L << 2));
            float* qp = &S.Q[row][L << 2];
            qp[0] = v.x; qp[1] = v.y; qp[2] = v.z; qp[3] = v.w;
        }
        __syncthreads();
        #pragma unroll
        for (int i = 0; i < 8; ++i) {
            int c = w * 64 + i * 8 + cidx;
            int p0 = pg * 4;
            float4 qv;
            qv.x = S.Q[p0 + 0][c]; qv.y = S.Q[p0 + 1][c];
            qv.z = S.Q[p0 + 2][c]; qv.w = S.Q[p0 + 3][c];
            *(float4*)(out + obase + ((size_t)c << 10) + ch * 32 + p0) = qv;
        }
    }
}

// ---------------------------------------------------------------------------
extern "C" void kernel_launch(void* const* d_in, const int* in_sizes, int n_in,
                              void* d_out, int out_size, void* d_ws, size_t ws_size,
                              hipStream_t stream) {
    const float* z  = (const float*)d_in[0];
    const float* cb = (const float*)d_in[1];
    float* out  = (float*)d_out;
    float* cn   = (float*)d_ws;                              // 4 KB
    uint2* cbf8 = (uint2*)((char*)d_ws + 4096);              // 256 KB
    float* loss = out + NELEM;

    prep_kernel<<<128, 256, 0, stream>>>(cb, cbf8, cn, loss);
    vq_kernel<<<512, 256, 0, stream>>>(z, (const uint4*)cbf8, cb, cn, out, loss);
}